// Round 1
// baseline (304.137 us; speedup 1.0000x reference)
//
#include <hip/hip_runtime.h>
#include <hip/hip_bf16.h>

#define LRELU_ALPHA 0.2f

typedef short bfrag8 __attribute__((ext_vector_type(8)));
typedef float accf4 __attribute__((ext_vector_type(4)));

__device__ __forceinline__ unsigned short f2bf(float x) {
    unsigned int u = __float_as_uint(x);
    u += 0x7FFFu + ((u >> 16) & 1u);   // round-to-nearest-even
    return (unsigned short)(u >> 16);
}
__device__ __forceinline__ float bf2f(unsigned short s) {
    return __uint_as_float(((unsigned int)s) << 16);
}

// ---------------------------------------------------------------------------
// Kernel 1: Wh[32768][256] = sent(32768x768,f32->bf16) @ W_w^T(bf16) + W_b
// 128x128 tile, BK=64, 4 waves, 16x16x32 bf16 MFMA, reg-staged LDS (padded 72)
// ---------------------------------------------------------------------------
__global__ __launch_bounds__(256) void gemm1_kernel(
    const float* __restrict__ sent, const float* __restrict__ Ww,
    const float* __restrict__ Wb, float* __restrict__ Wh)
{
    __shared__ unsigned short As[128][72];
    __shared__ unsigned short Bs[128][72];
    const int bid  = blockIdx.x;
    const int brow = bid >> 1, bcol = bid & 1;
    const int t    = threadIdx.x;
    const int lane = t & 63, w = t >> 6;
    const int wr = w >> 1, wc = w & 1;
    const int l15 = lane & 15, l4 = lane >> 4;
    accf4 acc[4][4];
    for (int i = 0; i < 4; ++i)
        for (int j = 0; j < 4; ++j)
            acc[i][j] = (accf4){0.f, 0.f, 0.f, 0.f};
    const int r0 = t >> 3;          // 0..31
    const int c8 = (t & 7) << 3;    // 0..56

    for (int k0 = 0; k0 < 768; k0 += 64) {
        for (int i = 0; i < 4; ++i) {
            const int r = (i << 5) + r0;
            const float* ga = &sent[(size_t)(brow * 128 + r) * 768 + k0 + c8];
            float4 v0 = *(const float4*)ga;
            float4 v1 = *(const float4*)(ga + 4);
            uint4 pk;
            pk.x = f2bf(v0.x) | ((unsigned)f2bf(v0.y) << 16);
            pk.y = f2bf(v0.z) | ((unsigned)f2bf(v0.w) << 16);
            pk.z = f2bf(v1.x) | ((unsigned)f2bf(v1.y) << 16);
            pk.w = f2bf(v1.z) | ((unsigned)f2bf(v1.w) << 16);
            *(uint4*)&As[r][c8] = pk;
            const float* gb = &Ww[(size_t)(bcol * 128 + r) * 768 + k0 + c8];
            float4 u0 = *(const float4*)gb;
            float4 u1 = *(const float4*)(gb + 4);
            uint4 qk;
            qk.x = f2bf(u0.x) | ((unsigned)f2bf(u0.y) << 16);
            qk.y = f2bf(u0.z) | ((unsigned)f2bf(u0.w) << 16);
            qk.z = f2bf(u1.x) | ((unsigned)f2bf(u1.y) << 16);
            qk.w = f2bf(u1.z) | ((unsigned)f2bf(u1.w) << 16);
            *(uint4*)&Bs[r][c8] = qk;
        }
        __syncthreads();
        for (int kk = 0; kk < 2; ++kk) {
            const int ka = (kk << 5) + (l4 << 3);
            bfrag8 af[4], bfg[4];
            for (int mi = 0; mi < 4; ++mi)
                af[mi] = *(const bfrag8*)&As[(wr << 6) + (mi << 4) + l15][ka];
            for (int ni = 0; ni < 4; ++ni)
                bfg[ni] = *(const bfrag8*)&Bs[(wc << 6) + (ni << 4) + l15][ka];
            for (int mi = 0; mi < 4; ++mi)
                for (int ni = 0; ni < 4; ++ni)
                    acc[mi][ni] = __builtin_amdgcn_mfma_f32_16x16x32_bf16(
                        af[mi], bfg[ni], acc[mi][ni], 0, 0, 0);
        }
        __syncthreads();
    }
    for (int ni = 0; ni < 4; ++ni) {
        const int gcol = bcol * 128 + (wc << 6) + (ni << 4) + l15;
        const float wb = Wb[gcol];
        for (int mi = 0; mi < 4; ++mi) {
            const int growb = brow * 128 + (wr << 6) + (mi << 4) + (l4 << 2);
            for (int reg = 0; reg < 4; ++reg)
                Wh[(size_t)(growb + reg) * 256 + gcol] = acc[mi][ni][reg] + wb;
        }
    }
}

// ---------------------------------------------------------------------------
// Kernel 2: s1 = Wh@a1, s2 = Wh@a2 (f32), and WhT_bf16[b][col][m] transpose.
// One block = 32 rows of one batch. LDS transpose [32][257] (conflict-free).
// ---------------------------------------------------------------------------
__global__ __launch_bounds__(256) void s1s2t_kernel(
    const float* __restrict__ Wh, const float* __restrict__ aw,
    float* __restrict__ s1, float* __restrict__ s2,
    unsigned short* __restrict__ WhT)
{
    __shared__ float T[32][257];
    const int bid = blockIdx.x;
    const int b = bid >> 5, chunk = bid & 31;
    const int row0 = chunk << 5;
    const int t = threadIdx.x;
    const int r = t >> 3, cg = (t & 7) << 5;
    const int grow = (b << 10) + row0 + r;
    const float* src = &Wh[(size_t)grow * 256 + cg];
    float p1 = 0.f, p2 = 0.f;
    for (int u = 0; u < 32; u += 4) {
        float4 v = *(const float4*)(src + u);
        T[r][cg + u]     = v.x; T[r][cg + u + 1] = v.y;
        T[r][cg + u + 2] = v.z; T[r][cg + u + 3] = v.w;
        const float* a1 = &aw[cg + u];
        const float* a2 = &aw[256 + cg + u];
        p1 += v.x * a1[0] + v.y * a1[1] + v.z * a1[2] + v.w * a1[3];
        p2 += v.x * a2[0] + v.y * a2[1] + v.z * a2[2] + v.w * a2[3];
    }
    p1 += __shfl_xor(p1, 1); p1 += __shfl_xor(p1, 2); p1 += __shfl_xor(p1, 4);
    p2 += __shfl_xor(p2, 1); p2 += __shfl_xor(p2, 2); p2 += __shfl_xor(p2, 4);
    if ((t & 7) == 0) { s1[grow] = p1; s2[grow] = p2; }
    __syncthreads();
    const int c = t;   // 0..255 output column
    const size_t obase = ((size_t)((b << 8) + c) << 10) + row0;
    for (int q = 0; q < 4; ++q) {
        const int rr = q << 3;
        uint4 pk;
        pk.x = f2bf(T[rr + 0][c]) | ((unsigned)f2bf(T[rr + 1][c]) << 16);
        pk.y = f2bf(T[rr + 2][c]) | ((unsigned)f2bf(T[rr + 3][c]) << 16);
        pk.z = f2bf(T[rr + 4][c]) | ((unsigned)f2bf(T[rr + 5][c]) << 16);
        pk.w = f2bf(T[rr + 6][c]) | ((unsigned)f2bf(T[rr + 7][c]) << 16);
        *(uint4*)&WhT[obase + rr] = pk;
    }
}

// ---------------------------------------------------------------------------
// Kernel 3: s2max[b] = max_m s2[b][m]  (softmax row-max via lrelu monotonicity)
// ---------------------------------------------------------------------------
__global__ __launch_bounds__(256) void s2max_kernel(
    const float* __restrict__ s2, float* __restrict__ s2max)
{
    const int b = blockIdx.x;
    const int t = threadIdx.x;
    float m = -1e30f;
    for (int i = t; i < 1024; i += 256) m = fmaxf(m, s2[(b << 10) + i]);
    for (int d = 1; d < 64; d <<= 1) m = fmaxf(m, __shfl_xor(m, d));
    __shared__ float red[4];
    if ((t & 63) == 0) red[t >> 6] = m;
    __syncthreads();
    if (t == 0) s2max[b] = fmaxf(fmaxf(red[0], red[1]), fmaxf(red[2], red[3]));
}

// ---------------------------------------------------------------------------
// Kernel 4: flash attention GEMM2 + elu + mean-pool.
// Per block: 128 n-rows x 128 out-cols of one batch. m-loop in tiles of 64:
// P-tile = exp(lrelu(s1+s2)-M) computed into LDS (bf16), B = WhT staged,
// MFMA accumulate; Z tracked (sum of the ROUNDED P so rows normalize exactly).
// ---------------------------------------------------------------------------
__global__ __launch_bounds__(256) void flash_kernel(
    const unsigned short* __restrict__ WhT, const float* __restrict__ s1g,
    const float* __restrict__ s2g, const float* __restrict__ s2maxg,
    float* __restrict__ pooled)
{
    __shared__ unsigned short Ps[128][72];
    __shared__ unsigned short Bs[128][72];
    __shared__ float s2s[1024];
    __shared__ float s1s[128];
    __shared__ float ms[128];
    __shared__ float zred[2][128];
    __shared__ float zfull[128];
    const int bid = blockIdx.x;
    const int b = bid >> 4, sub = bid & 15;
    const int n0 = (sub >> 1) << 7, col0 = (sub & 1) << 7;
    const int t = threadIdx.x;
    const int lane = t & 63, w = t >> 6;
    const int wr = w >> 1, wc = w & 1;
    const int l15 = lane & 15, l4 = lane >> 4;
    const float s2mx = s2maxg[b];
    for (int i = t; i < 1024; i += 256) s2s[i] = s2g[(b << 10) + i];
    if (t < 128) {
        float v = s1g[(b << 10) + n0 + t];
        s1s[t] = v;
        float x = v + s2mx;
        ms[t] = x > 0.f ? x : LRELU_ALPHA * x;   // exact row max of e
    }
    accf4 acc[4][4];
    for (int i = 0; i < 4; ++i)
        for (int j = 0; j < 4; ++j)
            acc[i][j] = (accf4){0.f, 0.f, 0.f, 0.f};
    float zpart = 0.f;
    const int pr = t & 127, half = t >> 7;
    const int bc = t >> 1, mh = (t & 1) << 5;
    __syncthreads();
    const float s1r = s1s[pr], Mr = ms[pr];
    for (int mt = 0; mt < 16; ++mt) {
        const int m0 = mt << 6;
        // compute P tile [128][64] -> bf16 LDS
        for (int g = 0; g < 4; ++g) {
            const int j8 = (half << 5) + (g << 3);
            unsigned int pw[4];
            for (int u2 = 0; u2 < 4; ++u2) {
                float x0 = s1r + s2s[m0 + j8 + (u2 << 1)];
                float x1 = s1r + s2s[m0 + j8 + (u2 << 1) + 1];
                x0 = x0 > 0.f ? x0 : LRELU_ALPHA * x0;
                x1 = x1 > 0.f ? x1 : LRELU_ALPHA * x1;
                unsigned short b0 = f2bf(__expf(x0 - Mr));
                unsigned short b1 = f2bf(__expf(x1 - Mr));
                zpart += bf2f(b0) + bf2f(b1);
                pw[u2] = (unsigned)b0 | ((unsigned)b1 << 16);
            }
            uint4 pk; pk.x = pw[0]; pk.y = pw[1]; pk.z = pw[2]; pk.w = pw[3];
            *(uint4*)&Ps[pr][j8] = pk;
        }
        // stage WhT tile [128 cols][64 m]
        {
            const unsigned short* src =
                &WhT[(((size_t)(b << 8) + col0 + bc) << 10) + m0 + mh];
            for (int q = 0; q < 4; ++q)
                *(uint4*)&Bs[bc][mh + (q << 3)] = *(const uint4*)(src + (q << 3));
        }
        __syncthreads();
        for (int kk = 0; kk < 2; ++kk) {
            const int ka = (kk << 5) + (l4 << 3);
            bfrag8 af[4], bfg[4];
            for (int mi = 0; mi < 4; ++mi)
                af[mi] = *(const bfrag8*)&Ps[(wr << 6) + (mi << 4) + l15][ka];
            for (int ni = 0; ni < 4; ++ni)
                bfg[ni] = *(const bfrag8*)&Bs[(wc << 6) + (ni << 4) + l15][ka];
            for (int mi = 0; mi < 4; ++mi)
                for (int ni = 0; ni < 4; ++ni)
                    acc[mi][ni] = __builtin_amdgcn_mfma_f32_16x16x32_bf16(
                        af[mi], bfg[ni], acc[mi][ni], 0, 0, 0);
        }
        __syncthreads();
    }
    zred[half][pr] = zpart;
    __syncthreads();
    if (t < 128) zfull[t] = zred[0][t] + zred[1][t];
    __syncthreads();
    // normalize, elu, pool (sum over the wave's 64 rows), atomic into pooled
    for (int ni = 0; ni < 4; ++ni) {
        const int gcol = col0 + (wc << 6) + (ni << 4) + l15;
        float hsum = 0.f;
        for (int mi = 0; mi < 4; ++mi) {
            const int rb = (wr << 6) + (mi << 4) + (l4 << 2);
            for (int reg = 0; reg < 4; ++reg) {
                float v = acc[mi][ni][reg] / zfull[rb + reg];
                hsum += v > 0.f ? v : expm1f(v);
            }
        }
        hsum += __shfl_xor(hsum, 16);
        hsum += __shfl_xor(hsum, 32);
        if (lane < 16) atomicAdd(&pooled[(b << 8) + gcol], hsum);
    }
}

// ---------------------------------------------------------------------------
// Kernel 5: out[b][k] = (pooled_sum[b]/1024) @ mlp_w[k] + mlp_b[k]
// ---------------------------------------------------------------------------
__global__ void final_kernel(const float* __restrict__ pooled,
                             const float* __restrict__ mlpw,
                             const float* __restrict__ mlpb,
                             float* __restrict__ out)
{
    const int t = threadIdx.x;     // 64 threads: (b,k)
    const int b = t >> 1, k = t & 1;
    float acc = 0.f;
    for (int o = 0; o < 256; ++o)
        acc += pooled[(b << 8) + o] * mlpw[(k << 8) + o];
    out[b * 2 + k] = acc * (1.0f / 1024.0f) + mlpb[k];
}

extern "C" void kernel_launch(void* const* d_in, const int* in_sizes, int n_in,
                              void* d_out, int out_size, void* d_ws, size_t ws_size,
                              hipStream_t stream) {
    const float* sent = (const float*)d_in[0];
    // d_in[1] = batch_e: provably unused (event_mask>0 is always true)
    const float* Ww   = (const float*)d_in[2];
    const float* Wb   = (const float*)d_in[3];
    const float* aw   = (const float*)d_in[4];
    const float* mlpw = (const float*)d_in[5];
    const float* mlpb = (const float*)d_in[6];
    float* out = (float*)d_out;

    char* ws = (char*)d_ws;
    // layout (total ~48.3 MiB)
    float*          Wh     = (float*)ws;                               // 33,554,432 B
    unsigned short* WhT    = (unsigned short*)(ws + 33554432);         // 16,777,216 B
    float*          s1     = (float*)(ws + 33554432 + 16777216);      //    131,072 B
    float*          s2     = s1 + 32768;                               //    131,072 B
    float*          s2mx   = s2 + 32768;                               //        256 B
    float*          pooled = s2mx + 64;                                //     32,768 B

    hipMemsetAsync(pooled, 0, 32 * 256 * sizeof(float), stream);
    gemm1_kernel<<<512, 256, 0, stream>>>(sent, Ww, Wb, Wh);
    s1s2t_kernel<<<1024, 256, 0, stream>>>(Wh, aw, s1, s2, WhT);
    s2max_kernel<<<32, 256, 0, stream>>>(s2, s2mx);
    flash_kernel<<<512, 256, 0, stream>>>(WhT, s1, s2, s2mx, pooled);
    final_kernel<<<1, 64, 0, stream>>>(pooled, mlpw, mlpb, out);
}

// Round 2
// 208.724 us; speedup vs baseline: 1.4571x; 1.4571x over previous
//
#include <hip/hip_runtime.h>
#include <hip/hip_bf16.h>

#define LOG2E 1.4426950408889634f

typedef short bfrag8 __attribute__((ext_vector_type(8)));
typedef float accf4 __attribute__((ext_vector_type(4)));

__device__ __forceinline__ unsigned pack2(float a, float b) {
    __hip_bfloat162 h = __float22bfloat162_rn(make_float2(a, b));
    return *(unsigned*)&h;
}
__device__ __forceinline__ float bflo(unsigned u) { return __uint_as_float(u << 16); }
__device__ __forceinline__ float bfhi(unsigned u) { return __uint_as_float(u & 0xFFFF0000u); }

__device__ __forceinline__ void gload_lds16(const void* g, void* lds) {
    __builtin_amdgcn_global_load_lds(
        (const __attribute__((address_space(1))) unsigned int*)g,
        (__attribute__((address_space(3))) unsigned int*)lds, 16, 0, 0);
}

// ---------------------------------------------------------------------------
// Kernel 1: fused GEMM1 + transpose + s1/s2 partials.
//   WhT[b][col][m] = bf16( sent@Ww^T + Wb )   (B-operand layout for flash)
//   s1part[bcol][row] = sum_cols Wh*a1*log2e (per col-half), same s2part.
// 128x128 tile, BK=64, 4 waves. XCD swizzle pairs (brow,bcol 0/1) on one L2.
// ---------------------------------------------------------------------------
__global__ __launch_bounds__(256) void gemm1_kernel(
    const float* __restrict__ sent, const float* __restrict__ Ww,
    const float* __restrict__ Wb, const float* __restrict__ aw,
    unsigned short* __restrict__ WhT, float* __restrict__ s1part,
    float* __restrict__ s2part)
{
    __shared__ unsigned short SM[2][128][72];   // As=SM[0], Bs=SM[1]; epilogue reuses as T[128][136]
    __shared__ float sb1[128][2];
    __shared__ float sb2[128][2];
    const int bid0 = blockIdx.x;
    const int wg = ((bid0 & 7) << 6) + (bid0 >> 3);   // XCD-contig (512 = 8*64, bijective)
    const int brow = wg >> 1, bcol = wg & 1;
    const int t    = threadIdx.x;
    const int lane = t & 63, w = t >> 6;
    const int wr = w >> 1, wc = w & 1;
    const int l15 = lane & 15, l4 = lane >> 4;
    accf4 acc[4][4];
#pragma unroll
    for (int i = 0; i < 4; ++i)
#pragma unroll
        for (int j = 0; j < 4; ++j)
            acc[i][j] = (accf4){0.f, 0.f, 0.f, 0.f};
    const int r0 = t >> 3;          // 0..31
    const int c8 = (t & 7) << 3;    // 0..56

    for (int k0 = 0; k0 < 768; k0 += 64) {
#pragma unroll
        for (int i = 0; i < 4; ++i) {
            const int r = (i << 5) + r0;
            const float* ga = &sent[(size_t)(brow * 128 + r) * 768 + k0 + c8];
            float4 v0 = *(const float4*)ga;
            float4 v1 = *(const float4*)(ga + 4);
            uint4 pk;
            pk.x = pack2(v0.x, v0.y); pk.y = pack2(v0.z, v0.w);
            pk.z = pack2(v1.x, v1.y); pk.w = pack2(v1.z, v1.w);
            *(uint4*)&SM[0][r][c8] = pk;
            const float* gb = &Ww[(size_t)(bcol * 128 + r) * 768 + k0 + c8];
            float4 u0 = *(const float4*)gb;
            float4 u1 = *(const float4*)(gb + 4);
            uint4 qk;
            qk.x = pack2(u0.x, u0.y); qk.y = pack2(u0.z, u0.w);
            qk.z = pack2(u1.x, u1.y); qk.w = pack2(u1.z, u1.w);
            *(uint4*)&SM[1][r][c8] = qk;
        }
        __syncthreads();
#pragma unroll
        for (int kk = 0; kk < 2; ++kk) {
            const int ka = (kk << 5) + (l4 << 3);
            bfrag8 af[4], bfg[4];
#pragma unroll
            for (int mi = 0; mi < 4; ++mi)
                af[mi] = *(const bfrag8*)&SM[0][(wr << 6) + (mi << 4) + l15][ka];
#pragma unroll
            for (int ni = 0; ni < 4; ++ni)
                bfg[ni] = *(const bfrag8*)&SM[1][(wc << 6) + (ni << 4) + l15][ka];
#pragma unroll
            for (int mi = 0; mi < 4; ++mi)
#pragma unroll
                for (int ni = 0; ni < 4; ++ni)
                    acc[mi][ni] = __builtin_amdgcn_mfma_f32_16x16x32_bf16(
                        af[mi], bfg[ni], acc[mi][ni], 0, 0, 0);
        }
        __syncthreads();
    }

    // ---- epilogue: bias, T (transpose) in LDS, s1/s2 partials ----
    unsigned short (*T)[136] = reinterpret_cast<unsigned short(*)[136]>(&SM[0][0][0]); // 34,816 B <= 36,864
    float sp1[16], sp2[16];
#pragma unroll
    for (int i = 0; i < 16; ++i) { sp1[i] = 0.f; sp2[i] = 0.f; }
#pragma unroll
    for (int ni = 0; ni < 4; ++ni) {
        const int colL = (wc << 6) + (ni << 4) + l15;
        const int gcol = bcol * 128 + colL;
        const float wb  = Wb[gcol];
        const float a1c = aw[gcol] * LOG2E;
        const float a2c = aw[256 + gcol] * LOG2E;
#pragma unroll
        for (int mi = 0; mi < 4; ++mi) {
            const int rowL = (wr << 6) + (mi << 4) + (l4 << 2);
            float v0 = acc[mi][ni][0] + wb, v1 = acc[mi][ni][1] + wb;
            float v2 = acc[mi][ni][2] + wb, v3 = acc[mi][ni][3] + wb;
            uint2 pk; pk.x = pack2(v0, v1); pk.y = pack2(v2, v3);
            *(uint2*)&T[colL][rowL] = pk;   // pad 136: stride 272B -> 2-way banks, 8B aligned
            sp1[mi * 4 + 0] += v0 * a1c; sp1[mi * 4 + 1] += v1 * a1c;
            sp1[mi * 4 + 2] += v2 * a1c; sp1[mi * 4 + 3] += v3 * a1c;
            sp2[mi * 4 + 0] += v0 * a2c; sp2[mi * 4 + 1] += v1 * a2c;
            sp2[mi * 4 + 2] += v2 * a2c; sp2[mi * 4 + 3] += v3 * a2c;
        }
    }
#pragma unroll
    for (int d = 1; d < 16; d <<= 1) {
#pragma unroll
        for (int i = 0; i < 16; ++i) {
            sp1[i] += __shfl_xor(sp1[i], d);
            sp2[i] += __shfl_xor(sp2[i], d);
        }
    }
    if (l15 == 0) {
#pragma unroll
        for (int mi = 0; mi < 4; ++mi)
#pragma unroll
            for (int reg = 0; reg < 4; ++reg) {
                const int rowL = (wr << 6) + (mi << 4) + (l4 << 2) + reg;
                sb1[rowL][wc] = sp1[mi * 4 + reg];
                sb2[rowL][wc] = sp2[mi * 4 + reg];
            }
    }
    __syncthreads();
    // coalesced WhT write-out: thread -> (col, half), 128B contiguous in m
    {
        const int b = brow >> 3, m0b = (brow & 7) << 7;
        const int colL = t >> 1, half = t & 1;
        const int gcol = bcol * 128 + colL;
        unsigned short* dst = &WhT[(((size_t)(b << 8) + gcol) << 10) + m0b + (half << 6)];
        const unsigned short* srcT = &T[colL][half << 6];
#pragma unroll
        for (int q = 0; q < 8; ++q)
            *(uint4*)(dst + (q << 3)) = *(const uint4*)(srcT + (q << 3));
    }
    if (t < 128) {
        const int grow = brow * 128 + t;
        s1part[bcol * 32768 + grow] = sb1[t][0] + sb1[t][1];
        s2part[bcol * 32768 + grow] = sb2[t][0] + sb2[t][1];
    }
}

// ---------------------------------------------------------------------------
// Kernel 2: flash attention GEMM2 + elu + per-block pooled partials.
// Block = 64 n-rows x 256 cols (full width, no P recompute), 8 waves (2x4).
// m-steps of 64: P=exp2(lrelu-M) -> swizzled Ps; B double-buffered via
// global_load_lds with source-side XOR swizzle (conflict-free ds_read_b128).
// No atomics: pooled_part[b][nt][col] plain store.
// ---------------------------------------------------------------------------
__global__ __launch_bounds__(512) void flash_kernel(
    const unsigned short* __restrict__ WhT,
    const float* __restrict__ s1part, const float* __restrict__ s2part,
    float* __restrict__ pooled_part)
{
    __shared__ unsigned short Bs[2][256][64];  // 65,536 B (linear, src-swizzled)
    __shared__ unsigned short Ps[64][64];      //  8,192 B (XOR-swizzled rows)
    __shared__ float s2s[1024];
    __shared__ float zfull[64];
    __shared__ float wred[8];
    __shared__ float psum[2][256];
    const int bid0 = blockIdx.x;
    const int wg = ((bid0 & 7) << 6) + (bid0 >> 3);   // batch's 16 blocks -> one XCD
    const int b = wg >> 4, nt = wg & 15, n0 = nt << 6;
    const int t = threadIdx.x;
    const int lane = t & 63, w = t >> 6;
    const int wr = w >> 2, wc = w & 3;
    const int l15 = lane & 15, l4 = lane >> 4;
    const int prow = t >> 3, pchk = t & 7;
    const unsigned short* wbase = WhT + (((size_t)b) << 18);

    // stage s2s = s2part0+s2part1 (already log2e-scaled)
    {
        const int i = t << 1;
        float2 p0 = *(const float2*)&s2part[(b << 10) + i];
        float2 p1 = *(const float2*)&s2part[32768 + (b << 10) + i];
        s2s[i] = p0.x + p1.x; s2s[i + 1] = p0.y + p1.y;
    }
    // prefetch B tile for m0=0 into Bs[0] (src-side swizzle: chunk c ^= row&7)
#pragma unroll
    for (int q = 0; q < 4; ++q) {
        const int r = (q << 6) + (w << 3) + (lane >> 3);
        const int c = (lane & 7) ^ (r & 7);
        gload_lds16(wbase + (((size_t)r) << 10) + (c << 3),
                    (char*)&Bs[0][0][0] + (q << 13) + (w << 10));
    }
    const float s1r = s1part[(b << 10) + n0 + prow] +
                      s1part[32768 + (b << 10) + n0 + prow];
    __syncthreads();
    // s2max (per-block; trivial) -> Mr = lrelu(s1+s2max) in log2 domain
    float mm = fmaxf(s2s[t], s2s[t + 512]);
#pragma unroll
    for (int d = 1; d < 64; d <<= 1) mm = fmaxf(mm, __shfl_xor(mm, d));
    if (lane == 0) wred[w] = mm;
    __syncthreads();
    float s2mx = wred[0];
#pragma unroll
    for (int i = 1; i < 8; ++i) s2mx = fmaxf(s2mx, wred[i]);
    const float xm = s1r + s2mx;
    const float Mr = fmaxf(xm, 0.2f * xm);

    accf4 acc[2][4];
#pragma unroll
    for (int i = 0; i < 2; ++i)
#pragma unroll
        for (int j = 0; j < 4; ++j)
            acc[i][j] = (accf4){0.f, 0.f, 0.f, 0.f};
    float zp = 0.f;

    for (int mt = 0; mt < 16; ++mt) {
        const int m0 = mt << 6;
        if (mt < 15) {   // prefetch next B tile (overlaps P-compute)
#pragma unroll
            for (int q = 0; q < 4; ++q) {
                const int r = (q << 6) + (w << 3) + (lane >> 3);
                const int c = (lane & 7) ^ (r & 7);
                gload_lds16(wbase + (((size_t)r) << 10) + (m0 + 64) + (c << 3),
                            (char*)&Bs[(mt + 1) & 1][0][0] + (q << 13) + (w << 10));
            }
        }
        // P tile: 8 elements/thread (row=prow, m-chunk=pchk)
        {
            const float* s2p = &s2s[m0 + (pchk << 3)];
            float4 sa = *(const float4*)s2p;
            float4 sb = *(const float4*)(s2p + 4);
#define LR(x) fmaxf((x), 0.2f * (x))
            float p0 = __builtin_amdgcn_exp2f(LR(s1r + sa.x) - Mr);
            float p1 = __builtin_amdgcn_exp2f(LR(s1r + sa.y) - Mr);
            float p2 = __builtin_amdgcn_exp2f(LR(s1r + sa.z) - Mr);
            float p3 = __builtin_amdgcn_exp2f(LR(s1r + sa.w) - Mr);
            float p4 = __builtin_amdgcn_exp2f(LR(s1r + sb.x) - Mr);
            float p5 = __builtin_amdgcn_exp2f(LR(s1r + sb.y) - Mr);
            float p6 = __builtin_amdgcn_exp2f(LR(s1r + sb.z) - Mr);
            float p7 = __builtin_amdgcn_exp2f(LR(s1r + sb.w) - Mr);
#undef LR
            unsigned u0 = pack2(p0, p1), u1 = pack2(p2, p3);
            unsigned u2 = pack2(p4, p5), u3 = pack2(p6, p7);
            zp += bflo(u0) + bfhi(u0) + bflo(u1) + bfhi(u1)
                + bflo(u2) + bfhi(u2) + bflo(u3) + bfhi(u3);   // Z of ROUNDED P
            uint4 pk; pk.x = u0; pk.y = u1; pk.z = u2; pk.w = u3;
            *(uint4*)((char*)&Ps[0][0] + (prow << 7) + ((pchk << 4) ^ ((prow & 7) << 4))) = pk;
        }
        __syncthreads();   // Ps + Bs[cur] ready (drains gll)
        const int cur = mt & 1;
#pragma unroll
        for (int kk = 0; kk < 2; ++kk) {
            const int kb = (kk << 6) + (l4 << 4);
            bfrag8 af[2], bf[4];
#pragma unroll
            for (int mi = 0; mi < 2; ++mi) {
                const int row = (wr << 5) + (mi << 4) + l15;
                af[mi] = *(const bfrag8*)((char*)&Ps[0][0] + (row << 7) + (kb ^ ((row & 7) << 4)));
            }
#pragma unroll
            for (int ni = 0; ni < 4; ++ni) {
                const int col = (wc << 6) + (ni << 4) + l15;
                bf[ni] = *(const bfrag8*)((char*)&Bs[cur][0][0] + (col << 7) + (kb ^ ((col & 7) << 4)));
            }
#pragma unroll
            for (int mi = 0; mi < 2; ++mi)
#pragma unroll
                for (int ni = 0; ni < 4; ++ni)
                    acc[mi][ni] = __builtin_amdgcn_mfma_f32_16x16x32_bf16(
                        af[mi], bf[ni], acc[mi][ni], 0, 0, 0);
        }
        __syncthreads();   // protect Ps/Bs for next iter
    }

    // Z: reduce the 8 threads sharing each row
    zp += __shfl_xor(zp, 1); zp += __shfl_xor(zp, 2); zp += __shfl_xor(zp, 4);
    if ((lane & 7) == 0) zfull[prow] = zp;
    __syncthreads();

    // epilogue: normalize, elu, column sums over this block's 64 rows
    float rz[8];
#pragma unroll
    for (int mi = 0; mi < 2; ++mi)
#pragma unroll
        for (int r = 0; r < 4; ++r)
            rz[mi * 4 + r] = 1.0f / zfull[(wr << 5) + (mi << 4) + (l4 << 2) + r];
#pragma unroll
    for (int ni = 0; ni < 4; ++ni) {
        float cs = 0.f;
#pragma unroll
        for (int mi = 0; mi < 2; ++mi)
#pragma unroll
            for (int r = 0; r < 4; ++r) {
                float v = acc[mi][ni][r] * rz[mi * 4 + r];
                cs += v > 0.f ? v : (__expf(v) - 1.0f);
            }
        cs += __shfl_xor(cs, 16);
        cs += __shfl_xor(cs, 32);
        if (l4 == 0) psum[wr][(wc << 6) + (ni << 4) + l15] = cs;
    }
    __syncthreads();
    if (t < 256)
        pooled_part[(((size_t)b << 4) + nt) * 256 + t] = psum[0][t] + psum[1][t];
}

// ---------------------------------------------------------------------------
// Kernel 3: reduce 16 n-tile partials, mean-pool, tiny MLP. One block per b.
// ---------------------------------------------------------------------------
__global__ __launch_bounds__(256) void final_kernel(
    const float* __restrict__ pooled_part, const float* __restrict__ mlpw,
    const float* __restrict__ mlpb, float* __restrict__ out)
{
    __shared__ float r0[4], r1[4];
    const int b = blockIdx.x, t = threadIdx.x;
    float p = 0.f;
#pragma unroll
    for (int ntile = 0; ntile < 16; ++ntile)
        p += pooled_part[(((size_t)b << 4) + ntile) * 256 + t];
    float m0 = p * mlpw[t], m1 = p * mlpw[256 + t];
#pragma unroll
    for (int d = 1; d < 64; d <<= 1) {
        m0 += __shfl_xor(m0, d);
        m1 += __shfl_xor(m1, d);
    }
    if ((t & 63) == 0) { r0[t >> 6] = m0; r1[t >> 6] = m1; }
    __syncthreads();
    if (t == 0) out[b * 2 + 0] = (r0[0] + r0[1] + r0[2] + r0[3]) * (1.f / 1024.f) + mlpb[0];
    if (t == 1) out[b * 2 + 1] = (r1[0] + r1[1] + r1[2] + r1[3]) * (1.f / 1024.f) + mlpb[1];
}

extern "C" void kernel_launch(void* const* d_in, const int* in_sizes, int n_in,
                              void* d_out, int out_size, void* d_ws, size_t ws_size,
                              hipStream_t stream) {
    const float* sent = (const float*)d_in[0];
    // d_in[1] = batch_e: provably unused (event_mask = where(cond,0.9,0.1) > 0 always)
    const float* Ww   = (const float*)d_in[2];
    const float* Wb   = (const float*)d_in[3];
    const float* aw   = (const float*)d_in[4];
    const float* mlpw = (const float*)d_in[5];
    const float* mlpb = (const float*)d_in[6];
    float* out = (float*)d_out;

    char* ws = (char*)d_ws;
    unsigned short* WhT    = (unsigned short*)ws;                 // 16,777,216 B
    float*          s1part = (float*)(ws + 16777216);             //    262,144 B (2 x 32768)
    float*          s2part = s1part + 65536;                      //    262,144 B
    float*          ppart  = s2part + 65536;                      //    524,288 B (32*16*256)

    gemm1_kernel<<<512, 256, 0, stream>>>(sent, Ww, Wb, aw, WhT, s1part, s2part);
    flash_kernel<<<512, 512, 0, stream>>>(WhT, s1part, s2part, ppart);
    final_kernel<<<32, 256, 0, stream>>>(ppart, mlpw, mlpb, out);
}

// Round 4
// 204.150 us; speedup vs baseline: 1.4898x; 1.0224x over previous
//
#include <hip/hip_runtime.h>
#include <hip/hip_bf16.h>

#define LOG2E 1.4426950408889634f

typedef short bfrag8 __attribute__((ext_vector_type(8)));
typedef float accf4 __attribute__((ext_vector_type(4)));

__device__ __forceinline__ unsigned pack2(float a, float b) {
    __hip_bfloat162 h = __float22bfloat162_rn(make_float2(a, b));
    return *(unsigned*)&h;
}
__device__ __forceinline__ float bflo(unsigned u) { return __uint_as_float(u << 16); }
__device__ __forceinline__ float bfhi(unsigned u) { return __uint_as_float(u & 0xFFFF0000u); }

__device__ __forceinline__ void gload_lds16(const void* g, void* lds) {
    __builtin_amdgcn_global_load_lds(
        (const __attribute__((address_space(1))) unsigned int*)g,
        (__attribute__((address_space(3))) unsigned int*)lds, 16, 0, 0);
}

// ---------------------------------------------------------------------------
// Kernel 0: Ww f32[256][768] -> bf16 (so gemm1's B staging is pure gload_lds)
// ---------------------------------------------------------------------------
__global__ __launch_bounds__(256) void convW_kernel(
    const float* __restrict__ Ww, unsigned short* __restrict__ WwB)
{
    const int id = (blockIdx.x * 256 + threadIdx.x) * 8;   // 96*256*8 = 196608 exact
    float4 a = *(const float4*)&Ww[id];
    float4 b = *(const float4*)&Ww[id + 4];
    uint4 pk;
    pk.x = pack2(a.x, a.y); pk.y = pack2(a.z, a.w);
    pk.z = pack2(b.x, b.y); pk.w = pack2(b.z, b.w);
    *(uint4*)&WwB[id] = pk;
}

// ---------------------------------------------------------------------------
// Kernel 1: Wh = sent @ Ww^T + Wb ; outputs WhT bf16 [b][col][m], s1, s2
// (s1,s2 pre-scaled by LOG2E). Tile 128Mx256N (full width), BK=64, 12 iters,
// 512 thr (8 waves 2x4), 1 block/CU. 2-phase: gload_lds dbuf (A f32, B bf16),
// source-side XOR swizzle, cvt f32->bf16 at ds_read. HBM-bound by design.
// Static LDS = exactly 128 KiB (verified envelope); epilogue scratch overlays.
// ---------------------------------------------------------------------------
__global__ __launch_bounds__(512) void gemm1_kernel(
    const float* __restrict__ sent, const unsigned short* __restrict__ WwB,
    const float* __restrict__ Wb, const float* __restrict__ aw,
    unsigned short* __restrict__ WhT, float* __restrict__ s1g,
    float* __restrict__ s2g)
{
    __shared__ char SMEM[131072];   // As f32 [2][128][64] @0 (64K) | Bs bf16 [2][256][64] @64K (64K)
    const int brow = blockIdx.x;          // 0..255
    const int t = threadIdx.x;
    const int lane = t & 63, w = t >> 6;
    const int wr = w >> 2, wc = w & 3;
    const int l15 = lane & 15, l4 = lane >> 4;
    const float* abase = sent + (size_t)brow * 128 * 768;

    accf4 acc[4][4];
#pragma unroll
    for (int i = 0; i < 4; ++i)
#pragma unroll
        for (int j = 0; j < 4; ++j)
            acc[i][j] = (accf4){0.f, 0.f, 0.f, 0.f};

    auto STAGE = [&](int buf, int k0) {
#pragma unroll
        for (int q = 0; q < 4; ++q) {          // A: 2048 x 16B chunks, f32
            const int id = (q << 9) + t;
            const int row = id >> 4, c = id & 15;
            gload_lds16(abase + (size_t)row * 768 + k0 + ((c ^ (row & 15)) << 2),
                        SMEM + (buf << 15) + (id << 4));
        }
#pragma unroll
        for (int q = 0; q < 4; ++q) {          // B: 2048 x 16B chunks, bf16
            const int id = (q << 9) + t;
            const int col = id >> 3, c = id & 7;
            gload_lds16(WwB + (size_t)col * 768 + k0 + ((c ^ (col & 7)) << 3),
                        SMEM + 65536 + (buf << 15) + (id << 4));
        }
    };

    auto COMPUTE = [&](int buf) {
        const float* Ab = (const float*)(SMEM + (buf << 15));
        const unsigned short* Bb = (const unsigned short*)(SMEM + 65536 + (buf << 15));
#pragma unroll
        for (int kk = 0; kk < 2; ++kk) {
            bfrag8 af[4], bf[4];
#pragma unroll
            for (int mi = 0; mi < 4; ++mi) {
                const int row = (wr << 6) + (mi << 4) + l15;
                const int s0 = (kk << 3) + (l4 << 1);
                float4 a0 = *(const float4*)(Ab + (row << 6) + ((s0 ^ (row & 15)) << 2));
                float4 a1 = *(const float4*)(Ab + (row << 6) + (((s0 + 1) ^ (row & 15)) << 2));
                uint4 pk;
                pk.x = pack2(a0.x, a0.y); pk.y = pack2(a0.z, a0.w);
                pk.z = pack2(a1.x, a1.y); pk.w = pack2(a1.z, a1.w);
                af[mi] = *(bfrag8*)&pk;
            }
#pragma unroll
            for (int ni = 0; ni < 4; ++ni) {
                const int col = (wc << 6) + (ni << 4) + l15;
                const int s = (kk << 2) + l4;
                bf[ni] = *(const bfrag8*)(Bb + (col << 6) + ((s ^ (col & 7)) << 3));
            }
#pragma unroll
            for (int mi = 0; mi < 4; ++mi)
#pragma unroll
                for (int ni = 0; ni < 4; ++ni)
                    acc[mi][ni] = __builtin_amdgcn_mfma_f32_16x16x32_bf16(
                        af[mi], bf[ni], acc[mi][ni], 0, 0, 0);
        }
    };

    STAGE(0, 0);
    __syncthreads();
    for (int it = 0; it < 12; ++it) {
        if (it < 11) STAGE((it + 1) & 1, (it + 1) << 6);
        COMPUTE(it & 1);
        __syncthreads();
    }

    // ---- epilogue: bias, transpose T[col][row] in LDS, s1/s2 ----
    // T occupies SMEM[0, 69632); sb1/sb2 overlay SMEM[98304, 102400) — both
    // regions are dead staging space after the final barrier above.
    unsigned short (*T)[136] = (unsigned short(*)[136])SMEM;
    float (*sb1)[4] = (float(*)[4])(SMEM + 98304);
    float (*sb2)[4] = (float(*)[4])(SMEM + 100352);
    float sp1[16], sp2[16];
#pragma unroll
    for (int i = 0; i < 16; ++i) { sp1[i] = 0.f; sp2[i] = 0.f; }
#pragma unroll
    for (int ni = 0; ni < 4; ++ni) {
        const int colL = (wc << 6) + (ni << 4) + l15;
        const float wb  = Wb[colL];
        const float a1c = aw[colL] * LOG2E;
        const float a2c = aw[256 + colL] * LOG2E;
#pragma unroll
        for (int mi = 0; mi < 4; ++mi) {
            const int rowL = (wr << 6) + (mi << 4) + (l4 << 2);
            float v0 = acc[mi][ni][0] + wb, v1 = acc[mi][ni][1] + wb;
            float v2 = acc[mi][ni][2] + wb, v3 = acc[mi][ni][3] + wb;
            uint2 pk; pk.x = pack2(v0, v1); pk.y = pack2(v2, v3);
            *(uint2*)&T[colL][rowL] = pk;
            sp1[mi * 4 + 0] += v0 * a1c; sp1[mi * 4 + 1] += v1 * a1c;
            sp1[mi * 4 + 2] += v2 * a1c; sp1[mi * 4 + 3] += v3 * a1c;
            sp2[mi * 4 + 0] += v0 * a2c; sp2[mi * 4 + 1] += v1 * a2c;
            sp2[mi * 4 + 2] += v2 * a2c; sp2[mi * 4 + 3] += v3 * a2c;
        }
    }
#pragma unroll
    for (int d = 1; d < 16; d <<= 1)
#pragma unroll
        for (int i = 0; i < 16; ++i) {
            sp1[i] += __shfl_xor(sp1[i], d);
            sp2[i] += __shfl_xor(sp2[i], d);
        }
    if (l15 == 0)
#pragma unroll
        for (int mi = 0; mi < 4; ++mi)
#pragma unroll
            for (int reg = 0; reg < 4; ++reg) {
                const int rowL = (wr << 6) + (mi << 4) + (l4 << 2) + reg;
                sb1[rowL][wc] = sp1[mi * 4 + reg];
                sb2[rowL][wc] = sp2[mi * 4 + reg];
            }
    __syncthreads();
    {   // WhT write: thread -> (col, half-row-block), 128B contiguous m
        const int b = brow >> 3, m0 = (brow & 7) << 7;
        const int col = t >> 1, half = t & 1;
        unsigned short* dst = &WhT[(((size_t)b * 256 + col) << 10) + m0 + (half << 6)];
        const unsigned short* srcT = &T[col][half << 6];
#pragma unroll
        for (int q = 0; q < 8; ++q)
            *(uint4*)(dst + (q << 3)) = *(const uint4*)(srcT + (q << 3));
    }
    if (t < 128) {
        const int grow = brow * 128 + t;
        s1g[grow] = sb1[t][0] + sb1[t][1] + sb1[t][2] + sb1[t][3];
        s2g[grow] = sb2[t][0] + sb2[t][1] + sb2[t][2] + sb2[t][3];
    }
}

// ---------------------------------------------------------------------------
// Kernel 2: flash GEMM2 + elu + pooled partials. 128 rows x 256 cols/block,
// 8 blocks/batch (XCD-grouped), 512 thr. One barrier per m-step: Bs dbuf via
// gload_lds (src-swizzled) + Ps dbuf (compute P(t+1) while MFMA(t)).
// ---------------------------------------------------------------------------
__global__ __launch_bounds__(512) void flash_kernel(
    const unsigned short* __restrict__ WhT, const float* __restrict__ s1g,
    const float* __restrict__ s2g, float* __restrict__ ppart)
{
    __shared__ char SMEM[98304];   // Bs [2][256][64]bf16 @0 (64K) | Ps [2][128][64]bf16 @64K (32K)
    __shared__ float s2s[1024];
    __shared__ float zfull[128];
    __shared__ float wred[8];
    __shared__ float psum[2][256];
    const int bid0 = blockIdx.x;
    const int wg = ((bid0 & 7) << 5) + (bid0 >> 3);   // 256=8x32 bijective; batch's 8 blocks -> 1 XCD
    const int b = wg >> 3, nt = wg & 7, n0 = nt << 7;
    const int t = threadIdx.x;
    const int lane = t & 63, w = t >> 6;
    const int wr = w >> 2, wc = w & 3;
    const int l15 = lane & 15, l4 = lane >> 4;
    const int prow = t >> 2, pc0 = (t & 3) << 1;      // P-thread: row, chunk pair
    const unsigned short* wbase = WhT + ((size_t)b << 18);

    {   // s2s = s2 (log2-domain)
        const int i = t << 1;
        *(float2*)&s2s[i] = *(const float2*)&s2g[(b << 10) + i];
    }
    auto STAGEB = [&](int buf, int m0) {
#pragma unroll
        for (int q = 0; q < 4; ++q) {
            const int id = (q << 9) + t;
            const int col = id >> 3, c = id & 7;
            gload_lds16(wbase + ((size_t)col << 10) + m0 + ((c ^ (col & 7)) << 3),
                        SMEM + (buf << 15) + (id << 4));
        }
    };
    STAGEB(0, 0);
    const float s1r = s1g[(b << 10) + n0 + prow];
    __syncthreads();                                   // s2s visible + B0 drained
    float mm = fmaxf(s2s[t], s2s[t + 512]);
#pragma unroll
    for (int d = 1; d < 64; d <<= 1) mm = fmaxf(mm, __shfl_xor(mm, d));
    if (lane == 0) wred[w] = mm;
    __syncthreads();
    float s2mx = wred[0];
#pragma unroll
    for (int i = 1; i < 8; ++i) s2mx = fmaxf(s2mx, wred[i]);
    const float xm = s1r + s2mx;
    const float Mr = fmaxf(xm, 0.2f * xm);             // exact row max (lrelu monotone)

    accf4 acc[4][4];
#pragma unroll
    for (int i = 0; i < 4; ++i)
#pragma unroll
        for (int j = 0; j < 4; ++j)
            acc[i][j] = (accf4){0.f, 0.f, 0.f, 0.f};
    float zp = 0.f;

    auto PCOMP = [&](int buf, int mt) {
        const float* sp = &s2s[(mt << 6) + (pc0 << 3)];
        float4 x0 = *(const float4*)sp;
        float4 x1 = *(const float4*)(sp + 4);
        float4 x2 = *(const float4*)(sp + 8);
        float4 x3 = *(const float4*)(sp + 12);
        float xs[16] = {x0.x, x0.y, x0.z, x0.w, x1.x, x1.y, x1.z, x1.w,
                        x2.x, x2.y, x2.z, x2.w, x3.x, x3.y, x3.z, x3.w};
        unsigned u[8];
#pragma unroll
        for (int j = 0; j < 8; ++j) {
            float a = s1r + xs[2 * j], c = s1r + xs[2 * j + 1];
            a = fmaxf(a, 0.2f * a) - Mr;
            c = fmaxf(c, 0.2f * c) - Mr;
            u[j] = pack2(__builtin_amdgcn_exp2f(a), __builtin_amdgcn_exp2f(c));
            zp += bflo(u[j]) + bfhi(u[j]);             // Z of ROUNDED P
        }
        char* pb = SMEM + 65536 + (buf << 14) + (prow << 7);
        uint4 k0; k0.x = u[0]; k0.y = u[1]; k0.z = u[2]; k0.w = u[3];
        uint4 k1; k1.x = u[4]; k1.y = u[5]; k1.z = u[6]; k1.w = u[7];
        *(uint4*)(pb + ((pc0 ^ (prow & 7)) << 4)) = k0;
        *(uint4*)(pb + (((pc0 + 1) ^ (prow & 7)) << 4)) = k1;
    };
    auto MM = [&](int buf) {
        const unsigned short* Bb = (const unsigned short*)(SMEM + (buf << 15));
        const char* Pb = SMEM + 65536 + (buf << 14);
#pragma unroll
        for (int kk = 0; kk < 2; ++kk) {
            bfrag8 af[4], bf[4];
#pragma unroll
            for (int mi = 0; mi < 4; ++mi) {
                const int row = (wr << 6) + (mi << 4) + l15;
                const int s = (kk << 2) + l4;
                af[mi] = *(const bfrag8*)(Pb + (row << 7) + ((s ^ (row & 7)) << 4));
            }
#pragma unroll
            for (int ni = 0; ni < 4; ++ni) {
                const int col = (wc << 6) + (ni << 4) + l15;
                const int s = (kk << 2) + l4;
                bf[ni] = *(const bfrag8*)(Bb + (col << 6) + ((s ^ (col & 7)) << 3));
            }
#pragma unroll
            for (int mi = 0; mi < 4; ++mi)
#pragma unroll
                for (int ni = 0; ni < 4; ++ni)
                    acc[mi][ni] = __builtin_amdgcn_mfma_f32_16x16x32_bf16(
                        af[mi], bf[ni], acc[mi][ni], 0, 0, 0);
        }
    };

    PCOMP(0, 0);
    __syncthreads();                                   // Ps[0] visible
    for (int mt = 0; mt < 16; ++mt) {
        if (mt < 15) {
            STAGEB((mt + 1) & 1, (mt + 1) << 6);       // async next B
            PCOMP((mt + 1) & 1, mt + 1);               // next P while MFMA below
        }
        MM(mt & 1);
        __syncthreads();                               // drain B(t+1), publish Ps(t+1)
    }

    // Z: 4 threads per row
    zp += __shfl_xor(zp, 1);
    zp += __shfl_xor(zp, 2);
    if ((lane & 3) == 0) zfull[prow] = zp;
    __syncthreads();

    // normalize, elu, column sums over 128 rows
    float rz[16];
#pragma unroll
    for (int mi = 0; mi < 4; ++mi)
#pragma unroll
        for (int r = 0; r < 4; ++r)
            rz[mi * 4 + r] = 1.0f / zfull[(wr << 6) + (mi << 4) + (l4 << 2) + r];
#pragma unroll
    for (int ni = 0; ni < 4; ++ni) {
        float cs = 0.f;
#pragma unroll
        for (int mi = 0; mi < 4; ++mi)
#pragma unroll
            for (int r = 0; r < 4; ++r) {
                float v = acc[mi][ni][r] * rz[mi * 4 + r];
                cs += v > 0.f ? v : (__expf(v) - 1.0f);
            }
        cs += __shfl_xor(cs, 16);
        cs += __shfl_xor(cs, 32);
        if (l4 == 0) psum[wr][(wc << 6) + (ni << 4) + l15] = cs;
    }
    __syncthreads();
    if (t < 256)
        ppart[(((size_t)b << 3) + nt) * 256 + t] = psum[0][t] + psum[1][t];
}

// ---------------------------------------------------------------------------
// Kernel 3: reduce 8 n-tile partials, mean-pool, tiny MLP. One block per b.
// ---------------------------------------------------------------------------
__global__ __launch_bounds__(256) void final_kernel(
    const float* __restrict__ ppart, const float* __restrict__ mlpw,
    const float* __restrict__ mlpb, float* __restrict__ out)
{
    __shared__ float r0[4], r1[4];
    const int b = blockIdx.x, t = threadIdx.x;
    float p = 0.f;
#pragma unroll
    for (int nt = 0; nt < 8; ++nt)
        p += ppart[(((size_t)b << 3) + nt) * 256 + t];
    float m0 = p * mlpw[t], m1 = p * mlpw[256 + t];
#pragma unroll
    for (int d = 1; d < 64; d <<= 1) {
        m0 += __shfl_xor(m0, d);
        m1 += __shfl_xor(m1, d);
    }
    if ((t & 63) == 0) { r0[t >> 6] = m0; r1[t >> 6] = m1; }
    __syncthreads();
    if (t == 0) out[b * 2 + 0] = (r0[0] + r0[1] + r0[2] + r0[3]) * (1.f / 1024.f) + mlpb[0];
    if (t == 1) out[b * 2 + 1] = (r1[0] + r1[1] + r1[2] + r1[3]) * (1.f / 1024.f) + mlpb[1];
}

extern "C" void kernel_launch(void* const* d_in, const int* in_sizes, int n_in,
                              void* d_out, int out_size, void* d_ws, size_t ws_size,
                              hipStream_t stream) {
    const float* sent = (const float*)d_in[0];
    // d_in[1] = batch_e: provably unused (event_mask = where(cond,0.9,0.1) > 0 always)
    const float* Ww   = (const float*)d_in[2];
    const float* Wb   = (const float*)d_in[3];
    const float* aw   = (const float*)d_in[4];
    const float* mlpw = (const float*)d_in[5];
    const float* mlpb = (const float*)d_in[6];
    float* out = (float*)d_out;

    char* ws = (char*)d_ws;
    unsigned short* WhT  = (unsigned short*)ws;              // 16,777,216 B
    unsigned short* WwB  = (unsigned short*)(ws + 16777216); //    393,216 B
    float*          s1g  = (float*)(ws + 17170432);          //    131,072 B
    float*          s2g  = s1g + 32768;                      //    131,072 B
    float*          ppart= s2g + 32768;                      //    262,144 B (32*8*256)

    convW_kernel<<<96, 256, 0, stream>>>(Ww, WwB);
    gemm1_kernel<<<256, 512, 0, stream>>>(sent, WwB, Wb, aw, WhT, s1g, s2g);
    flash_kernel<<<256, 512, 0, stream>>>(WhT, s1g, s2g, ppart);
    final_kernel<<<32, 256, 0, stream>>>(ppart, mlpw, mlpb, out);
}